// Round 21
// baseline (207.395 us; speedup 1.0000x reference)
//
#include <hip/hip_runtime.h>
#include <hip/hip_fp16.h>

#define N_NODES 20000
#define N_EDGES 640000
#define IN_F    2000
#define KPAD    2048
#define C_OUT   64
#define HC      256   // HEADS * C_OUT
#define NEG     0.2f
#define SCAN_B  79    // ceil(20000/256)

typedef __attribute__((ext_vector_type(4))) float f32x4;
typedef __attribute__((ext_vector_type(8))) short bf16x8;
typedef _Float16 h2 __attribute__((ext_vector_type(2)));    // packed fp16 pair
typedef _Float16 f16x8 __attribute__((ext_vector_type(8))); // MFMA f16 frag

__device__ inline unsigned short f2bf(float f) {
    unsigned u = __float_as_uint(f);
    return (unsigned short)((u + 0x7FFFu + ((u >> 16) & 1u)) >> 16);
}

// packed fp32x2 -> bf16x2 via HW converter (RTNE), gfx950
__device__ inline unsigned cvt_pk_bf16(float lo, float hi) {
    unsigned r;
    asm("v_cvt_pk_bf16_f32 %0, %1, %2" : "=v"(r) : "v"(lo), "v"(hi));
    return r;
}

// ---------------- CSR build ----------------

__global__ void k_hist(const int* __restrict__ dst, int* __restrict__ counts) {
    int e = blockIdx.x * blockDim.x + threadIdx.x;
    if (e < N_EDGES) atomicAdd(&counts[dst[e]], 1);
}

__global__ void k_scan1(const int* __restrict__ counts, int* __restrict__ bsum) {
    int t = threadIdx.x, b = blockIdx.x;
    int i = b * 256 + t;
    int v = (i < N_NODES) ? counts[i] : 0;
    int s = v;
    #pragma unroll
    for (int d = 1; d < 64; d <<= 1) s += __shfl_xor(s, d, 64);
    __shared__ int ws[4];
    if ((t & 63) == 0) ws[t >> 6] = s;
    __syncthreads();
    if (t == 0) bsum[b] = ws[0] + ws[1] + ws[2] + ws[3];
}

__global__ void k_scan2(const int* __restrict__ bsum, int* __restrict__ bbase,
                        int* __restrict__ offsets) {
    int lane = threadIdx.x;   // 64 threads
    int v0 = (lane < SCAN_B) ? bsum[lane] : 0;
    int v1 = (64 + lane < SCAN_B) ? bsum[64 + lane] : 0;
    int s0 = v0;
    #pragma unroll
    for (int d = 1; d < 64; d <<= 1) { int t = __shfl_up(s0, d, 64); if (lane >= d) s0 += t; }
    int tot0 = __shfl(s0, 63, 64);
    int s1 = v1;
    #pragma unroll
    for (int d = 1; d < 64; d <<= 1) { int t = __shfl_up(s1, d, 64); if (lane >= d) s1 += t; }
    int tot1 = __shfl(s1, 63, 64);
    if (lane < SCAN_B) bbase[lane] = s0 - v0;
    if (64 + lane < SCAN_B) bbase[64 + lane] = tot0 + s1 - v1;
    if (lane == 0) offsets[N_NODES] = tot0 + tot1;
}

__global__ void k_scan3(const int* __restrict__ counts, const int* __restrict__ bbase,
                        int* __restrict__ offsets, int* __restrict__ cursor) {
    int t = threadIdx.x, b = blockIdx.x;
    int lane = t & 63, wid = t >> 6;
    int i = b * 256 + t;
    int v = (i < N_NODES) ? counts[i] : 0;
    int s = v;
    #pragma unroll
    for (int d = 1; d < 64; d <<= 1) { int u = __shfl_up(s, d, 64); if (lane >= d) s += u; }
    __shared__ int ws[4];
    if (lane == 63) ws[wid] = s;
    __syncthreads();
    int wb = 0;
    #pragma unroll
    for (int w = 0; w < 3; ++w) if (w < wid) wb += ws[w];
    int excl = bbase[b] + wb + (s - v);
    if (i < N_NODES) { offsets[i] = excl; cursor[i] = excl; }
}

__global__ void k_scatter(const int* __restrict__ src, const int* __restrict__ dst,
                          int* __restrict__ cursor, int* __restrict__ ssrc) {
    int e = blockIdx.x * blockDim.x + threadIdx.x;
    if (e < N_EDGES) {
        int d = dst[e];
        int p = atomicAdd(&cursor[d], 1);
        ssrc[p] = src[e];
    }
}

// -------- Wpk = W_ae^T bf16, fragment-contiguous: [k>>3][col][k&7] ----------

__global__ void k_wt(const float* __restrict__ W, unsigned short* __restrict__ Wpk) {
    int idx = blockIdx.x * 256 + threadIdx.x;   // 64*2048 = 131072
    int n = idx >> 11;
    int k = idx & 2047;
    float v = (k < IN_F) ? W[(size_t)k * C_OUT + n] : 0.f;
    Wpk[(size_t)(k >> 3) * 512 + n * 8 + (k & 7)] = f2bf(v);
}

__global__ void k_wlin16(const float* __restrict__ W, unsigned short* __restrict__ Wt16) {
    int idx = blockIdx.x * 256 + threadIdx.x;   // 64*256 = 16384
    int col = idx >> 8;
    int k = idx & 255;
    _Float16 v = (_Float16)W[(size_t)k * C_OUT + col];
    Wt16[(size_t)col * HC + k] = __builtin_bit_cast(unsigned short, v);
}

// ---------------- h = x @ W_ae + b_ae  (bf16 MFMA, split-K across 8 waves) --

__global__ __launch_bounds__(512) void k_gemm_h(
    const float* __restrict__ x, const unsigned short* __restrict__ Wpk,
    const float* __restrict__ b, float* __restrict__ h) {
    __shared__ float red[16][7][64];   // 28 KB
    int t = threadIdx.x;
    int lane = t & 63, w = t >> 6;     // w = 0..7
    int row0 = blockIdx.x * 16;        // 1250*16 = 20000 exact
    int r = lane & 15, kc = lane >> 4;
    const float* xrow = x + (size_t)(row0 + r) * IN_F;
    f32x4 acc[4] = {{0,0,0,0},{0,0,0,0},{0,0,0,0},{0,0,0,0}};

    int kstart = w * 256;
    #pragma unroll
    for (int s = 0; s < 8; ++s) {
        int kb = kstart + s * 32 + kc * 8;
        int kbc = kb <= 1992 ? kb : 1992;       // clamp keeps address in-bounds
        float4 f0 = *(const float4*)&xrow[kbc];
        float4 f1 = *(const float4*)&xrow[kbc + 4];
        uint4 uu;
        uu.x = cvt_pk_bf16(f0.x, f0.y);
        uu.y = cvt_pk_bf16(f0.z, f0.w);
        uu.z = cvt_pk_bf16(f1.x, f1.y);
        uu.w = cvt_pk_bf16(f1.z, f1.w);
        if (kb > 1992) { uu.x = 0u; uu.y = 0u; uu.z = 0u; uu.w = 0u; }
        bf16x8 af = __builtin_bit_cast(bf16x8, uu);
        const unsigned short* bp = Wpk + (size_t)(kb >> 3) * 512;
        #pragma unroll
        for (int cb = 0; cb < 4; ++cb) {
            bf16x8 bf = *(const bf16x8*)&bp[(cb * 16 + r) * 8];
            acc[cb] = __builtin_amdgcn_mfma_f32_16x16x32_bf16(af, bf, acc[cb], 0, 0, 0);
        }
    }

    if (w > 0) {
        #pragma unroll
        for (int cb = 0; cb < 4; ++cb)
            #pragma unroll
            for (int rr = 0; rr < 4; ++rr)
                red[cb * 4 + rr][w - 1][lane] = acc[cb][rr];
    }
    __syncthreads();
    if (w == 0) {
        #pragma unroll
        for (int cb = 0; cb < 4; ++cb)
            #pragma unroll
            for (int rr = 0; rr < 4; ++rr) {
                float s = acc[cb][rr];
                #pragma unroll
                for (int ww = 0; ww < 7; ++ww)
                    s += red[cb * 4 + rr][ww][lane];
                acc[cb][rr] = s;
            }
        int ci = kc * 4, cj = r;
        #pragma unroll
        for (int cb = 0; cb < 4; ++cb) {
            int col = cb * 16 + cj;
            float bb = b[col];
            #pragma unroll
            for (int rr = 0; rr < 4; ++rr)
                h[(size_t)(row0 + ci + rr) * C_OUT + col] = acc[cb][rr] + bb;
        }
    }
}

// ---------------- xl (fp16, HEAD-MAJOR [4][N][64]) | xr (fp32) ----------------

__global__ __launch_bounds__(256) void k_xlxr2(
    const float* __restrict__ h, const float* __restrict__ Wl, const float* __restrict__ bl,
    const float* __restrict__ Wr, const float* __restrict__ br,
    unsigned short* __restrict__ xlhm, float* __restrict__ xr) {
    __shared__ float hs[64][68];
    __shared__ float Ws[64][128];
    int t = threadIdx.x;
    int mb = blockIdx.x >> 2, nb = blockIdx.x & 3;
    int node0 = mb * 64;
    const float* Wsrc = (nb < 2) ? (Wl + nb * 128) : (Wr + (nb - 2) * 128);
    const float* bsrc = (nb < 2) ? (bl + nb * 128) : (br + (nb - 2) * 128);

    {
        int row = t >> 2, q = t & 3;
        int gnode = node0 + row; if (gnode >= N_NODES) gnode = N_NODES - 1;
        const float4* src = (const float4*)&h[(size_t)gnode * C_OUT + q * 16];
        *(float4*)&hs[row][q * 16 + 0]  = src[0];
        *(float4*)&hs[row][q * 16 + 4]  = src[1];
        *(float4*)&hs[row][q * 16 + 8]  = src[2];
        *(float4*)&hs[row][q * 16 + 12] = src[3];
    }
    {
        #pragma unroll
        for (int i = 0; i < 8; ++i) {
            int f = t + i * 256;
            int k = f >> 5, c4 = (f & 31) << 2;
            *(float4*)&Ws[k][c4] = *(const float4*)&Wsrc[(size_t)k * HC + c4];
        }
    }
    __syncthreads();

    int tr = t >> 5;
    int tc = t & 31;
    float4 acc[8];
    float4 bv = *(const float4*)&bsrc[tc * 4];
    #pragma unroll
    for (int r = 0; r < 8; ++r) acc[r] = bv;

    for (int k4 = 0; k4 < 64; k4 += 4) {
        float4 w0 = *(float4*)&Ws[k4 + 0][tc * 4];
        float4 w1 = *(float4*)&Ws[k4 + 1][tc * 4];
        float4 w2 = *(float4*)&Ws[k4 + 2][tc * 4];
        float4 w3 = *(float4*)&Ws[k4 + 3][tc * 4];
        #pragma unroll
        for (int r = 0; r < 8; ++r) {
            float4 a = *(float4*)&hs[tr * 8 + r][k4];
            acc[r].x += a.x * w0.x + a.y * w1.x + a.z * w2.x + a.w * w3.x;
            acc[r].y += a.x * w0.y + a.y * w1.y + a.z * w2.y + a.w * w3.y;
            acc[r].z += a.x * w0.z + a.y * w1.z + a.z * w2.z + a.w * w3.z;
            acc[r].w += a.x * w0.w + a.y * w1.w + a.z * w2.w + a.w * w3.w;
        }
    }
    #pragma unroll
    for (int r = 0; r < 8; ++r) {
        int gnode = node0 + tr * 8 + r;
        if (gnode < N_NODES) {
            if (nb < 2) {
                int col  = nb * 128 + tc * 4;   // 4 consecutive cols, one head
                int head = col >> 6;
                int chin = col & 63;
                h2 lo = { (_Float16)acc[r].x, (_Float16)acc[r].y };
                h2 hi = { (_Float16)acc[r].z, (_Float16)acc[r].w };
                uint2 o = { __builtin_bit_cast(unsigned, lo),
                            __builtin_bit_cast(unsigned, hi) };
                *(uint2*)&xlhm[((size_t)head * N_NODES + gnode) * 64 + chin] = o;
            } else {
                *(float4*)&xr[(size_t)gnode * HC + (nb - 2) * 128 + tc * 4] = acc[r];
            }
        }
    }
}

// ---------------- attention, HEAD-SPLIT (grid.y = head) -> ov (fp16) ----------
// Per (node, head): wave gathers 128B/edge from the 2.5MB per-head xl slice
// (fits per-XCD L2). 8 edges/wave (sub = lane>>3), 8 ch/lane; 2-deep pipeline;
// no LDS, no sync. Per-head softmax is independent => exact same math.

__global__ __launch_bounds__(256) void k_attn(
    const unsigned short* __restrict__ xlhm, const float* __restrict__ xr,
    const int* __restrict__ offsets, const int* __restrict__ ssrc,
    const float* __restrict__ att, const float* __restrict__ b_conv,
    unsigned short* __restrict__ ovh) {
    int wid = threadIdx.x >> 6, lane = threadIdx.x & 63;
    int node = blockIdx.x * 4 + wid;     // 5000*4 = 20000 exact
    int head = blockIdx.y;               // 0..3
    int sub = lane >> 3;     // edge slot 0..7
    int sl  = lane & 7;      // channel group (8 fp16)
    int cg  = head * 64 + sl * 8;        // global channel offset (node-major arrays)
    const unsigned short* xbase = xlhm + (size_t)head * N_NODES * 64 + sl * 8;

    const h2 z2  = { (_Float16)0.f, (_Float16)0.f };
    const h2 ns2 = { (_Float16)NEG, (_Float16)NEG };

    h2 xr2[4], at2[4];
    #pragma unroll
    for (int i = 0; i < 2; ++i) {
        float4 t4 = *(const float4*)&xr[(size_t)node * HC + cg + i * 4];
        xr2[i*2+0] = h2{ (_Float16)t4.x, (_Float16)t4.y };
        xr2[i*2+1] = h2{ (_Float16)t4.z, (_Float16)t4.w };
        float4 a4 = *(const float4*)&att[cg + i * 4];
        at2[i*2+0] = h2{ (_Float16)a4.x, (_Float16)a4.y };
        at2[i*2+1] = h2{ (_Float16)a4.z, (_Float16)a4.w };
    }
    h2 acc2[4];
    #pragma unroll
    for (int i = 0; i < 4; ++i) acc2[i] = z2;
    float denom = 0.f;

    auto load_edge = [&](int j, uint4& w0) {
        w0 = *(const uint4*)&xbase[(size_t)j * 64];
    };
    auto compute_edge = [&](uint4 w0, bool valid) {
        h2 x2[4];
        x2[0] = __builtin_bit_cast(h2, w0.x); x2[1] = __builtin_bit_cast(h2, w0.y);
        x2[2] = __builtin_bit_cast(h2, w0.z); x2[3] = __builtin_bit_cast(h2, w0.w);
        h2 p2 = z2;
        #pragma unroll
        for (int i = 0; i < 4; ++i) {
            h2 g  = x2[i] + xr2[i];
            h2 gs = g * ns2;
            g = __builtin_elementwise_max(g, gs);   // leaky: max(g, 0.2g), exact
            p2 += g * at2[i];
        }
        float p = (float)p2.x + (float)p2.y;
        p += __shfl_xor(p, 1); p += __shfl_xor(p, 2); p += __shfl_xor(p, 4); // 8 lanes = head
        float ex = valid ? __expf(p) : 0.f;             // logits O(1): no max shift
        denom += ex;
        h2 e2 = { (_Float16)ex, (_Float16)ex };
        #pragma unroll
        for (int i = 0; i < 4; ++i) acc2[i] += e2 * x2[i];
    };

    {   // self loop (counted once, slot 0)
        uint4 s0v;
        load_edge(node, s0v);
        compute_edge(s0v, sub == 0);
    }

    int s0 = offsets[node], s1 = offsets[node + 1];
    for (int base = s0; base < s1; base += 64) {
        int rem = s1 - base;
        int cnt = rem < 64 ? rem : 64;
        int jv = (base + lane < s1) ? ssrc[base + lane] : 0;
        int niter = (cnt + 7) >> 3;
        uint4 a0, b0;
        int jA = __shfl(jv, sub, 64);
        load_edge(jA, a0);
        for (int it = 0; it < niter; it += 2) {
            int eB = ((it + 1) << 3) + sub;
            int jB = __shfl(jv, eB & 63, 64);
            load_edge(jB, b0);                        // prefetch B under A's compute
            compute_edge(a0, ((it << 3) + sub) < cnt);
            int eA2 = ((it + 2) << 3) + sub;
            int jA2 = __shfl(jv, eA2 & 63, 64);
            load_edge(jA2, a0);                       // prefetch next A under B
            compute_edge(b0, eB < cnt);
        }
    }

    // unpack to fp32, reduce over the 8 edge slots
    float accf[8];
    #pragma unroll
    for (int i = 0; i < 4; ++i) {
        accf[2*i]   = (float)acc2[i].x;
        accf[2*i+1] = (float)acc2[i].y;
    }
    #pragma unroll
    for (int i = 0; i < 8; ++i) {
        accf[i] += __shfl_xor(accf[i], 8);
        accf[i] += __shfl_xor(accf[i], 16);
        accf[i] += __shfl_xor(accf[i], 32);
    }
    denom += __shfl_xor(denom, 8);
    denom += __shfl_xor(denom, 16);
    denom += __shfl_xor(denom, 32);

    float inv = 1.f / denom;
    if (sub == 0) {   // 8 lanes write 8 fp16 each (128B per node-head)
        float bcf[8];
        #pragma unroll
        for (int i = 0; i < 2; ++i) {
            float4 bc = *(const float4*)&b_conv[cg + i * 4];
            bcf[i*4+0] = bc.x; bcf[i*4+1] = bc.y; bcf[i*4+2] = bc.z; bcf[i*4+3] = bc.w;
        }
        unsigned ww[4];
        #pragma unroll
        for (int i = 0; i < 4; ++i) {
            h2 p = { (_Float16)(accf[2*i]   * inv + bcf[2*i]),
                     (_Float16)(accf[2*i+1] * inv + bcf[2*i+1]) };
            ww[i] = __builtin_bit_cast(unsigned, p);
        }
        uint4 o0 = { ww[0], ww[1], ww[2], ww[3] };
        *(uint4*)&ovh[(size_t)node * HC + cg] = o0;
    }
}

// ---------------- post: relu(ov @ W_lin + b_lin) + h -> LayerNorm -> out -----

__global__ __launch_bounds__(256) void k_post(
    const unsigned short* __restrict__ ovh, const unsigned short* __restrict__ Wt16,
    const float* __restrict__ b_lin, const float* __restrict__ hbuf,
    const float* __restrict__ ln_w, const float* __restrict__ ln_b,
    float* __restrict__ out) {
    int t = threadIdx.x;
    int lane = t & 63, w = t >> 6;
    int node0 = blockIdx.x * 64 + w * 16;
    int r = lane & 15, kc = lane >> 4;
    int noder = node0 + r;
    int nodec = noder < N_NODES ? noder : N_NODES - 1;

    f32x4 acc[4] = {{0,0,0,0},{0,0,0,0},{0,0,0,0},{0,0,0,0}};
    #pragma unroll
    for (int k0 = 0; k0 < HC; k0 += 32) {
        int kb = k0 + kc * 8;
        f16x8 af = *(const f16x8*)&ovh[(size_t)nodec * HC + kb];
        #pragma unroll
        for (int cb = 0; cb < 4; ++cb) {
            f16x8 bf = *(const f16x8*)&Wt16[(size_t)(cb * 16 + r) * HC + kb];
            acc[cb] = __builtin_amdgcn_mfma_f32_16x16x32_f16(af, bf, acc[cb], 0, 0, 0);
        }
    }

    int ci = (lane >> 4) * 4, cj = lane & 15;
    #pragma unroll
    for (int rr = 0; rr < 4; ++rr) {
        int grow = node0 + ci + rr;
        int growc = grow < N_NODES ? grow : N_NODES - 1;
        float y[4];
        float ssum = 0.f;
        #pragma unroll
        for (int cb = 0; cb < 4; ++cb) {
            int col = cb * 16 + cj;
            float a = acc[cb][rr] + b_lin[col];
            a = a > 0.f ? a : 0.f;
            float yy = a + hbuf[(size_t)growc * C_OUT + col];
            y[cb] = yy;
            ssum += yy;
        }
        ssum += __shfl_xor(ssum, 1); ssum += __shfl_xor(ssum, 2);
        ssum += __shfl_xor(ssum, 4); ssum += __shfl_xor(ssum, 8);
        float m = ssum * (1.f / 64.f);
        float vs = 0.f;
        #pragma unroll
        for (int cb = 0; cb < 4; ++cb) { float d = y[cb] - m; vs += d * d; }
        vs += __shfl_xor(vs, 1); vs += __shfl_xor(vs, 2);
        vs += __shfl_xor(vs, 4); vs += __shfl_xor(vs, 8);
        float rinv = rsqrtf(vs * (1.f / 64.f) + 1e-12f);
        if (grow < N_NODES) {
            #pragma unroll
            for (int cb = 0; cb < 4; ++cb) {
                int col = cb * 16 + cj;
                out[(size_t)grow * C_OUT + col] =
                    ln_w[col] * (y[cb] - m) * rinv + ln_b[col];
            }
        }
    }
}

// ---------------- launch ----------------

extern "C" void kernel_launch(void* const* d_in, const int* in_sizes, int n_in,
                              void* d_out, int out_size, void* d_ws, size_t ws_size,
                              hipStream_t stream) {
    const float* x     = (const float*)d_in[0];
    const int*   ei    = (const int*)  d_in[1];
    const float* W_ae  = (const float*)d_in[2];
    const float* b_ae  = (const float*)d_in[3];
    const float* Wl    = (const float*)d_in[4];
    const float* bl    = (const float*)d_in[5];
    const float* Wr    = (const float*)d_in[6];
    const float* br    = (const float*)d_in[7];
    const float* att   = (const float*)d_in[8];
    const float* b_conv= (const float*)d_in[9];
    const float* W_lin = (const float*)d_in[10];
    const float* b_lin = (const float*)d_in[11];
    const float* ln_w  = (const float*)d_in[12];
    const float* ln_b  = (const float*)d_in[13];
    float* out = (float*)d_out;
    const int* src = ei;
    const int* dst = ei + N_EDGES;

    char* ws = (char*)d_ws;
    size_t off = 0;
    auto alloc = [&](size_t bytes) {
        void* p = ws + off;
        off = (off + bytes + 255) & ~(size_t)255;
        return p;
    };
    float* h       = (float*)alloc((size_t)N_NODES * C_OUT * 4);
    unsigned short* xlhm = (unsigned short*)alloc((size_t)N_NODES * HC * 2);
    float* xr      = (float*)alloc((size_t)N_NODES * HC * 4);
    unsigned short* ovh = (unsigned short*)alloc((size_t)N_NODES * HC * 2);
    int*   counts  = (int*)  alloc((size_t)N_NODES * 4);
    int*   offsets = (int*)  alloc((size_t)(N_NODES + 1) * 4);
    int*   cursor  = (int*)  alloc((size_t)N_NODES * 4);
    int*   ssrc    = (int*)  alloc((size_t)N_EDGES * 4);
    unsigned short* Wpk  = (unsigned short*)alloc((size_t)C_OUT * KPAD * 2);
    unsigned short* Wt16 = (unsigned short*)alloc((size_t)C_OUT * HC * 2);
    int*   bsum    = (int*)  alloc((size_t)SCAN_B * 4);
    int*   bbase   = (int*)  alloc((size_t)SCAN_B * 4);

    (void)hipMemsetAsync(counts, 0, (size_t)N_NODES * 4, stream);
    k_hist   <<<(N_EDGES + 255) / 256, 256, 0, stream>>>(dst, counts);
    k_scan1  <<<SCAN_B, 256, 0, stream>>>(counts, bsum);
    k_scan2  <<<1, 64, 0, stream>>>(bsum, bbase, offsets);
    k_scan3  <<<SCAN_B, 256, 0, stream>>>(counts, bbase, offsets, cursor);
    k_scatter<<<(N_EDGES + 255) / 256, 256, 0, stream>>>(src, dst, cursor, ssrc);
    k_wt     <<<(C_OUT * KPAD) / 256, 256, 0, stream>>>(W_ae, Wpk);
    k_wlin16 <<<(C_OUT * HC) / 256, 256, 0, stream>>>(W_lin, Wt16);
    k_gemm_h <<<N_NODES / 16, 512, 0, stream>>>(x, Wpk, b_ae, h);
    k_xlxr2  <<<((N_NODES + 63) / 64) * 4, 256, 0, stream>>>(h, Wl, bl, Wr, br, xlhm, xr);
    k_attn   <<<dim3(N_NODES / 4, 4), 256, 0, stream>>>(xlhm, xr, offsets, ssrc,
                                                        att, b_conv, ovh);
    k_post   <<<(N_NODES + 63) / 64, 256, 0, stream>>>(ovh, Wt16, b_lin, h,
                                                       ln_w, ln_b, out);
}

// Round 22
// 183.097 us; speedup vs baseline: 1.1327x; 1.1327x over previous
//
#include <hip/hip_runtime.h>
#include <hip/hip_fp16.h>

#define N_NODES 20000
#define N_EDGES 640000
#define IN_F    2000
#define KPAD    2048
#define C_OUT   64
#define HC      256   // HEADS * C_OUT
#define NEG     0.2f
#define SCAN_B  79    // ceil(20000/256)

typedef __attribute__((ext_vector_type(4))) float f32x4;
typedef __attribute__((ext_vector_type(8))) short bf16x8;
typedef _Float16 h2 __attribute__((ext_vector_type(2)));    // packed fp16 pair
typedef _Float16 f16x8 __attribute__((ext_vector_type(8))); // MFMA f16 frag

__device__ inline unsigned short f2bf(float f) {
    unsigned u = __float_as_uint(f);
    return (unsigned short)((u + 0x7FFFu + ((u >> 16) & 1u)) >> 16);
}

__device__ inline unsigned cvt_pk_bf16(float lo, float hi) {
    unsigned r;
    asm("v_cvt_pk_bf16_f32 %0, %1, %2" : "=v"(r) : "v"(lo), "v"(hi));
    return r;
}

// ------- fused prep: Wpk repack | W_lin fp16 repack | edge histogram -------
// blocks [0,512): Wpk;  [512,576): Wt16;  [576,3076): hist. All independent.

__global__ __launch_bounds__(256) void k_prep(
    const float* __restrict__ W_ae, unsigned short* __restrict__ Wpk,
    const float* __restrict__ W_lin, unsigned short* __restrict__ Wt16,
    const int* __restrict__ dst, int* __restrict__ counts) {
    int b = blockIdx.x, t = threadIdx.x;
    if (b < 512) {                 // Wpk = W_ae^T bf16 frag-contig [k>>3][col][k&7]
        int idx = b * 256 + t;     // 64*2048 = 131072
        int n = idx >> 11;
        int k = idx & 2047;
        float v = (k < IN_F) ? W_ae[(size_t)k * C_OUT + n] : 0.f;
        Wpk[(size_t)(k >> 3) * 512 + n * 8 + (k & 7)] = f2bf(v);
    } else if (b < 576) {          // Wt16 = W_lin^T fp16
        int idx = (b - 512) * 256 + t;   // 64*256 = 16384
        int col = idx >> 8;
        int k = idx & 255;
        _Float16 v = (_Float16)W_lin[(size_t)k * C_OUT + col];
        Wt16[(size_t)col * HC + k] = __builtin_bit_cast(unsigned short, v);
    } else {                       // hist
        int e = (b - 576) * 256 + t;
        if (e < N_EDGES) atomicAdd(&counts[dst[e]], 1);
    }
}

// ---------------- scan (3 small kernels) ----------------

__global__ void k_scan1(const int* __restrict__ counts, int* __restrict__ bsum) {
    int t = threadIdx.x, b = blockIdx.x;
    int i = b * 256 + t;
    int v = (i < N_NODES) ? counts[i] : 0;
    int s = v;
    #pragma unroll
    for (int d = 1; d < 64; d <<= 1) s += __shfl_xor(s, d, 64);
    __shared__ int ws[4];
    if ((t & 63) == 0) ws[t >> 6] = s;
    __syncthreads();
    if (t == 0) bsum[b] = ws[0] + ws[1] + ws[2] + ws[3];
}

__global__ void k_scan2(const int* __restrict__ bsum, int* __restrict__ bbase,
                        int* __restrict__ offsets) {
    int lane = threadIdx.x;   // 64 threads
    int v0 = (lane < SCAN_B) ? bsum[lane] : 0;
    int v1 = (64 + lane < SCAN_B) ? bsum[64 + lane] : 0;
    int s0 = v0;
    #pragma unroll
    for (int d = 1; d < 64; d <<= 1) { int t = __shfl_up(s0, d, 64); if (lane >= d) s0 += t; }
    int tot0 = __shfl(s0, 63, 64);
    int s1 = v1;
    #pragma unroll
    for (int d = 1; d < 64; d <<= 1) { int t = __shfl_up(s1, d, 64); if (lane >= d) s1 += t; }
    int tot1 = __shfl(s1, 63, 64);
    if (lane < SCAN_B) bbase[lane] = s0 - v0;
    if (64 + lane < SCAN_B) bbase[64 + lane] = tot0 + s1 - v1;
    if (lane == 0) offsets[N_NODES] = tot0 + tot1;
}

__global__ void k_scan3(const int* __restrict__ counts, const int* __restrict__ bbase,
                        int* __restrict__ offsets, int* __restrict__ cursor) {
    int t = threadIdx.x, b = blockIdx.x;
    int lane = t & 63, wid = t >> 6;
    int i = b * 256 + t;
    int v = (i < N_NODES) ? counts[i] : 0;
    int s = v;
    #pragma unroll
    for (int d = 1; d < 64; d <<= 1) { int u = __shfl_up(s, d, 64); if (lane >= d) s += u; }
    __shared__ int ws[4];
    if (lane == 63) ws[wid] = s;
    __syncthreads();
    int wb = 0;
    #pragma unroll
    for (int w = 0; w < 3; ++w) if (w < wid) wb += ws[w];
    int excl = bbase[b] + wb + (s - v);
    if (i < N_NODES) { offsets[i] = excl; cursor[i] = excl; }
}

// -------- fused: h = x@W_ae+b (bf16 MFMA split-K, blocks 0..1249) |
//                 scatter (blocks 1250..2499), hidden under gemm --------

__global__ __launch_bounds__(512) void k_gemm_sc(
    const float* __restrict__ x, const unsigned short* __restrict__ Wpk,
    const float* __restrict__ b, float* __restrict__ h,
    const int* __restrict__ src, const int* __restrict__ dst,
    int* __restrict__ cursor, int* __restrict__ ssrc) {
    if (blockIdx.x >= 1250) {      // scatter: 1250 blocks x 512 thr = 640000
        int e = (blockIdx.x - 1250) * 512 + threadIdx.x;
        if (e < N_EDGES) {
            int d = dst[e];
            int p = atomicAdd(&cursor[d], 1);
            ssrc[p] = src[e];
        }
        return;
    }
    __shared__ float red[16][7][64];   // 28 KB
    int t = threadIdx.x;
    int lane = t & 63, w = t >> 6;     // w = 0..7
    int row0 = blockIdx.x * 16;        // 1250*16 = 20000 exact
    int r = lane & 15, kc = lane >> 4;
    const float* xrow = x + (size_t)(row0 + r) * IN_F;
    f32x4 acc[4] = {{0,0,0,0},{0,0,0,0},{0,0,0,0},{0,0,0,0}};

    int kstart = w * 256;
    #pragma unroll
    for (int s = 0; s < 8; ++s) {
        int kb = kstart + s * 32 + kc * 8;
        int kbc = kb <= 1992 ? kb : 1992;       // clamp keeps address in-bounds
        float4 f0 = *(const float4*)&xrow[kbc];
        float4 f1 = *(const float4*)&xrow[kbc + 4];
        uint4 uu;
        uu.x = cvt_pk_bf16(f0.x, f0.y);
        uu.y = cvt_pk_bf16(f0.z, f0.w);
        uu.z = cvt_pk_bf16(f1.x, f1.y);
        uu.w = cvt_pk_bf16(f1.z, f1.w);
        if (kb > 1992) { uu.x = 0u; uu.y = 0u; uu.z = 0u; uu.w = 0u; }
        bf16x8 af = __builtin_bit_cast(bf16x8, uu);
        const unsigned short* bp = Wpk + (size_t)(kb >> 3) * 512;
        #pragma unroll
        for (int cb = 0; cb < 4; ++cb) {
            bf16x8 bf = *(const bf16x8*)&bp[(cb * 16 + r) * 8];
            acc[cb] = __builtin_amdgcn_mfma_f32_16x16x32_bf16(af, bf, acc[cb], 0, 0, 0);
        }
    }

    if (w > 0) {
        #pragma unroll
        for (int cb = 0; cb < 4; ++cb)
            #pragma unroll
            for (int rr = 0; rr < 4; ++rr)
                red[cb * 4 + rr][w - 1][lane] = acc[cb][rr];
    }
    __syncthreads();
    if (w == 0) {
        #pragma unroll
        for (int cb = 0; cb < 4; ++cb)
            #pragma unroll
            for (int rr = 0; rr < 4; ++rr) {
                float s = acc[cb][rr];
                #pragma unroll
                for (int ww = 0; ww < 7; ++ww)
                    s += red[cb * 4 + rr][ww][lane];
                acc[cb][rr] = s;
            }
        int ci = kc * 4, cj = r;
        #pragma unroll
        for (int cb = 0; cb < 4; ++cb) {
            int col = cb * 16 + cj;
            float bb = b[col];
            #pragma unroll
            for (int rr = 0; rr < 4; ++rr)
                h[(size_t)(row0 + ci + rr) * C_OUT + col] = acc[cb][rr] + bb;
        }
    }
}

// ---------------- xl (fp16, node-major) | xr (fp32) = h @ [Wl|Wr] + [bl|br] --

__global__ __launch_bounds__(256) void k_xlxr2(
    const float* __restrict__ h, const float* __restrict__ Wl, const float* __restrict__ bl,
    const float* __restrict__ Wr, const float* __restrict__ br,
    unsigned short* __restrict__ xlh, float* __restrict__ xr) {
    __shared__ float hs[64][68];
    __shared__ float Ws[64][128];
    int t = threadIdx.x;
    int mb = blockIdx.x >> 2, nb = blockIdx.x & 3;
    int node0 = mb * 64;
    const float* Wsrc = (nb < 2) ? (Wl + nb * 128) : (Wr + (nb - 2) * 128);
    const float* bsrc = (nb < 2) ? (bl + nb * 128) : (br + (nb - 2) * 128);

    {
        int row = t >> 2, q = t & 3;
        int gnode = node0 + row; if (gnode >= N_NODES) gnode = N_NODES - 1;
        const float4* src = (const float4*)&h[(size_t)gnode * C_OUT + q * 16];
        *(float4*)&hs[row][q * 16 + 0]  = src[0];
        *(float4*)&hs[row][q * 16 + 4]  = src[1];
        *(float4*)&hs[row][q * 16 + 8]  = src[2];
        *(float4*)&hs[row][q * 16 + 12] = src[3];
    }
    {
        #pragma unroll
        for (int i = 0; i < 8; ++i) {
            int f = t + i * 256;
            int k = f >> 5, c4 = (f & 31) << 2;
            *(float4*)&Ws[k][c4] = *(const float4*)&Wsrc[(size_t)k * HC + c4];
        }
    }
    __syncthreads();

    int tr = t >> 5;
    int tc = t & 31;
    float4 acc[8];
    float4 bv = *(const float4*)&bsrc[tc * 4];
    #pragma unroll
    for (int r = 0; r < 8; ++r) acc[r] = bv;

    for (int k4 = 0; k4 < 64; k4 += 4) {
        float4 w0 = *(float4*)&Ws[k4 + 0][tc * 4];
        float4 w1 = *(float4*)&Ws[k4 + 1][tc * 4];
        float4 w2 = *(float4*)&Ws[k4 + 2][tc * 4];
        float4 w3 = *(float4*)&Ws[k4 + 3][tc * 4];
        #pragma unroll
        for (int r = 0; r < 8; ++r) {
            float4 a = *(float4*)&hs[tr * 8 + r][k4];
            acc[r].x += a.x * w0.x + a.y * w1.x + a.z * w2.x + a.w * w3.x;
            acc[r].y += a.x * w0.y + a.y * w1.y + a.z * w2.y + a.w * w3.y;
            acc[r].z += a.x * w0.z + a.y * w1.z + a.z * w2.z + a.w * w3.z;
            acc[r].w += a.x * w0.w + a.y * w1.w + a.z * w2.w + a.w * w3.w;
        }
    }
    #pragma unroll
    for (int r = 0; r < 8; ++r) {
        int gnode = node0 + tr * 8 + r;
        if (gnode < N_NODES) {
            if (nb < 2) {
                h2 lo = { (_Float16)acc[r].x, (_Float16)acc[r].y };
                h2 hi = { (_Float16)acc[r].z, (_Float16)acc[r].w };
                uint2 o = { __builtin_bit_cast(unsigned, lo),
                            __builtin_bit_cast(unsigned, hi) };
                *(uint2*)&xlh[(size_t)gnode * HC + nb * 128 + tc * 4] = o;
            } else {
                *(float4*)&xr[(size_t)gnode * HC + (nb - 2) * 128 + tc * 4] = acc[r];
            }
        }
    }
}

// ---------------- attention (round-20 form): 4 indep waves/block ----------------

__global__ __launch_bounds__(256) void k_attn(
    const unsigned short* __restrict__ xlh, const float* __restrict__ xr,
    const int* __restrict__ offsets, const int* __restrict__ ssrc,
    const float* __restrict__ att, const float* __restrict__ b_conv,
    unsigned short* __restrict__ ovh) {
    int wid = threadIdx.x >> 6, lane = threadIdx.x & 63;
    int node = blockIdx.x * 4 + wid;     // 5000*4 = 20000 exact
    int sub = lane >> 4;     // edge slot 0..3
    int sl  = lane & 15;     // channel group
    int c0  = sl * 16;

    const h2 z2  = { (_Float16)0.f, (_Float16)0.f };
    const h2 ns2 = { (_Float16)NEG, (_Float16)NEG };

    h2 xr2[8], at2[8];
    #pragma unroll
    for (int i = 0; i < 4; ++i) {
        float4 t4 = *(const float4*)&xr[(size_t)node * HC + c0 + i * 4];
        xr2[i*2+0] = h2{ (_Float16)t4.x, (_Float16)t4.y };
        xr2[i*2+1] = h2{ (_Float16)t4.z, (_Float16)t4.w };
        float4 a4 = *(const float4*)&att[c0 + i * 4];
        at2[i*2+0] = h2{ (_Float16)a4.x, (_Float16)a4.y };
        at2[i*2+1] = h2{ (_Float16)a4.z, (_Float16)a4.w };
    }
    h2 acc2[8];
    #pragma unroll
    for (int i = 0; i < 8; ++i) acc2[i] = z2;
    float denom = 0.f;

    auto load_edge = [&](int j, uint4& w0, uint4& w1) {
        const uint4* rp = (const uint4*)&xlh[(size_t)j * HC + c0];
        w0 = rp[0]; w1 = rp[1];
    };
    auto compute_edge = [&](uint4 w0, uint4 w1, bool valid) {
        h2 x2[8];
        x2[0] = __builtin_bit_cast(h2, w0.x); x2[1] = __builtin_bit_cast(h2, w0.y);
        x2[2] = __builtin_bit_cast(h2, w0.z); x2[3] = __builtin_bit_cast(h2, w0.w);
        x2[4] = __builtin_bit_cast(h2, w1.x); x2[5] = __builtin_bit_cast(h2, w1.y);
        x2[6] = __builtin_bit_cast(h2, w1.z); x2[7] = __builtin_bit_cast(h2, w1.w);
        h2 p2 = z2;
        #pragma unroll
        for (int i = 0; i < 8; ++i) {
            h2 g  = x2[i] + xr2[i];
            h2 gs = g * ns2;
            g = __builtin_elementwise_max(g, gs);   // leaky: max(g, 0.2g), exact
            p2 += g * at2[i];
        }
        float p = (float)p2.x + (float)p2.y;
        p += __shfl_xor(p, 1); p += __shfl_xor(p, 2);   // 4 lanes = one head
        float ex = valid ? __expf(p) : 0.f;             // logits O(1): no max shift
        denom += ex;
        h2 e2 = { (_Float16)ex, (_Float16)ex };
        #pragma unroll
        for (int i = 0; i < 8; ++i) acc2[i] += e2 * x2[i];
    };

    {   // self loop (counted once, slot 0)
        uint4 s0v, s1v;
        load_edge(node, s0v, s1v);
        compute_edge(s0v, s1v, sub == 0);
    }

    int s0 = offsets[node], s1 = offsets[node + 1];
    for (int base = s0; base < s1; base += 64) {
        int rem = s1 - base;
        int cnt = rem < 64 ? rem : 64;
        int jv = (base + lane < s1) ? ssrc[base + lane] : 0;
        int niter = (cnt + 3) >> 2;
        uint4 a0, a1, b0, b1;
        int jA = __shfl(jv, sub, 64);
        load_edge(jA, a0, a1);
        for (int it = 0; it < niter; it += 2) {
            int eB = ((it + 1) << 2) + sub;
            int jB = __shfl(jv, eB & 63, 64);
            load_edge(jB, b0, b1);                    // prefetch B under A's compute
            compute_edge(a0, a1, ((it << 2) + sub) < cnt);
            int eA2 = ((it + 2) << 2) + sub;
            int jA2 = __shfl(jv, eA2 & 63, 64);
            load_edge(jA2, a0, a1);                   // prefetch next A under B
            compute_edge(b0, b1, eB < cnt);
        }
    }

    // unpack to fp32, reduce over the 4 edge slots
    float accf[16];
    #pragma unroll
    for (int i = 0; i < 8; ++i) {
        accf[2*i]   = (float)acc2[i].x;
        accf[2*i+1] = (float)acc2[i].y;
    }
    #pragma unroll
    for (int i = 0; i < 16; ++i) {
        accf[i] += __shfl_xor(accf[i], 16);
        accf[i] += __shfl_xor(accf[i], 32);
    }
    denom += __shfl_xor(denom, 16);
    denom += __shfl_xor(denom, 32);

    float inv = 1.f / denom;
    if (sub == 0) {   // 16 lanes write 16 fp16 each
        float bcf[16];
        #pragma unroll
        for (int i = 0; i < 4; ++i) {
            float4 bc = *(const float4*)&b_conv[c0 + i * 4];
            bcf[i*4+0] = bc.x; bcf[i*4+1] = bc.y; bcf[i*4+2] = bc.z; bcf[i*4+3] = bc.w;
        }
        unsigned ww[8];
        #pragma unroll
        for (int i = 0; i < 8; ++i) {
            h2 p = { (_Float16)(accf[2*i]   * inv + bcf[2*i]),
                     (_Float16)(accf[2*i+1] * inv + bcf[2*i+1]) };
            ww[i] = __builtin_bit_cast(unsigned, p);
        }
        uint4 o0 = { ww[0], ww[1], ww[2], ww[3] };
        uint4 o1 = { ww[4], ww[5], ww[6], ww[7] };
        *(uint4*)&ovh[(size_t)node * HC + c0]     = o0;
        *(uint4*)&ovh[(size_t)node * HC + c0 + 8] = o1;
    }
}

// ---------------- post: relu(ov @ W_lin + b_lin) + h -> LayerNorm -> out -----

__global__ __launch_bounds__(256) void k_post(
    const unsigned short* __restrict__ ovh, const unsigned short* __restrict__ Wt16,
    const float* __restrict__ b_lin, const float* __restrict__ hbuf,
    const float* __restrict__ ln_w, const float* __restrict__ ln_b,
    float* __restrict__ out) {
    int t = threadIdx.x;
    int lane = t & 63, w = t >> 6;
    int node0 = blockIdx.x * 64 + w * 16;
    int r = lane & 15, kc = lane >> 4;
    int noder = node0 + r;
    int nodec = noder < N_NODES ? noder : N_NODES - 1;

    f32x4 acc[4] = {{0,0,0,0},{0,0,0,0},{0,0,0,0},{0,0,0,0}};
    #pragma unroll
    for (int k0 = 0; k0 < HC; k0 += 32) {
        int kb = k0 + kc * 8;
        f16x8 af = *(const f16x8*)&ovh[(size_t)nodec * HC + kb];
        #pragma unroll
        for (int cb = 0; cb < 4; ++cb) {
            f16x8 bf = *(const f16x8*)&Wt16[(size_t)(cb * 16 + r) * HC + kb];
            acc[cb] = __builtin_amdgcn_mfma_f32_16x16x32_f16(af, bf, acc[cb], 0, 0, 0);
        }
    }

    int ci = (lane >> 4) * 4, cj = lane & 15;
    #pragma unroll
    for (int rr = 0; rr < 4; ++rr) {
        int grow = node0 + ci + rr;
        int growc = grow < N_NODES ? grow : N_NODES - 1;
        float y[4];
        float ssum = 0.f;
        #pragma unroll
        for (int cb = 0; cb < 4; ++cb) {
            int col = cb * 16 + cj;
            float a = acc[cb][rr] + b_lin[col];
            a = a > 0.f ? a : 0.f;
            float yy = a + hbuf[(size_t)growc * C_OUT + col];
            y[cb] = yy;
            ssum += yy;
        }
        ssum += __shfl_xor(ssum, 1); ssum += __shfl_xor(ssum, 2);
        ssum += __shfl_xor(ssum, 4); ssum += __shfl_xor(ssum, 8);
        float m = ssum * (1.f / 64.f);
        float vs = 0.f;
        #pragma unroll
        for (int cb = 0; cb < 4; ++cb) { float d = y[cb] - m; vs += d * d; }
        vs += __shfl_xor(vs, 1); vs += __shfl_xor(vs, 2);
        vs += __shfl_xor(vs, 4); vs += __shfl_xor(vs, 8);
        float rinv = rsqrtf(vs * (1.f / 64.f) + 1e-12f);
        if (grow < N_NODES) {
            #pragma unroll
            for (int cb = 0; cb < 4; ++cb) {
                int col = cb * 16 + cj;
                out[(size_t)grow * C_OUT + col] =
                    ln_w[col] * (y[cb] - m) * rinv + ln_b[col];
            }
        }
    }
}

// ---------------- launch ----------------

extern "C" void kernel_launch(void* const* d_in, const int* in_sizes, int n_in,
                              void* d_out, int out_size, void* d_ws, size_t ws_size,
                              hipStream_t stream) {
    const float* x     = (const float*)d_in[0];
    const int*   ei    = (const int*)  d_in[1];
    const float* W_ae  = (const float*)d_in[2];
    const float* b_ae  = (const float*)d_in[3];
    const float* Wl    = (const float*)d_in[4];
    const float* bl    = (const float*)d_in[5];
    const float* Wr    = (const float*)d_in[6];
    const float* br    = (const float*)d_in[7];
    const float* att   = (const float*)d_in[8];
    const float* b_conv= (const float*)d_in[9];
    const float* W_lin = (const float*)d_in[10];
    const float* b_lin = (const float*)d_in[11];
    const float* ln_w  = (const float*)d_in[12];
    const float* ln_b  = (const float*)d_in[13];
    float* out = (float*)d_out;
    const int* src = ei;
    const int* dst = ei + N_EDGES;

    char* ws = (char*)d_ws;
    size_t off = 0;
    auto alloc = [&](size_t bytes) {
        void* p = ws + off;
        off = (off + bytes + 255) & ~(size_t)255;
        return p;
    };
    float* h       = (float*)alloc((size_t)N_NODES * C_OUT * 4);
    unsigned short* xlh = (unsigned short*)alloc((size_t)N_NODES * HC * 2);
    float* xr      = (float*)alloc((size_t)N_NODES * HC * 4);
    unsigned short* ovh = (unsigned short*)alloc((size_t)N_NODES * HC * 2);
    int*   counts  = (int*)  alloc((size_t)N_NODES * 4);
    int*   offsets = (int*)  alloc((size_t)(N_NODES + 1) * 4);
    int*   cursor  = (int*)  alloc((size_t)N_NODES * 4);
    int*   ssrc    = (int*)  alloc((size_t)N_EDGES * 4);
    unsigned short* Wpk  = (unsigned short*)alloc((size_t)C_OUT * KPAD * 2);
    unsigned short* Wt16 = (unsigned short*)alloc((size_t)C_OUT * HC * 2);
    int*   bsum    = (int*)  alloc((size_t)SCAN_B * 4);
    int*   bbase   = (int*)  alloc((size_t)SCAN_B * 4);

    (void)hipMemsetAsync(counts, 0, (size_t)N_NODES * 4, stream);
    k_prep   <<<576 + (N_EDGES + 255) / 256, 256, 0, stream>>>(W_ae, Wpk, W_lin, Wt16,
                                                               dst, counts);
    k_scan1  <<<SCAN_B, 256, 0, stream>>>(counts, bsum);
    k_scan2  <<<1, 64, 0, stream>>>(bsum, bbase, offsets);
    k_scan3  <<<SCAN_B, 256, 0, stream>>>(counts, bbase, offsets, cursor);
    k_gemm_sc<<<2500, 512, 0, stream>>>(x, Wpk, b_ae, h, src, dst, cursor, ssrc);
    k_xlxr2  <<<((N_NODES + 63) / 64) * 4, 256, 0, stream>>>(h, Wl, bl, Wr, br, xlh, xr);
    k_attn   <<<N_NODES / 4, 256, 0, stream>>>(xlh, xr, offsets, ssrc, att, b_conv, ovh);
    k_post   <<<(N_NODES + 63) / 64, 256, 0, stream>>>(ovh, Wt16, b_lin, h,
                                                       ln_w, ln_b, out);
}